// Round 15
// baseline (917.028 us; speedup 1.0000x reference)
//
#include <hip/hip_runtime.h>
#include <hip/hip_bf16.h>
#include <climits>

#define NB 2
#define NPTS_ 16384
#define IMH 200
#define IMW 176
#define IMC 256
#define HW_ (IMH * IMW)
#define KTOT_ 2048
#define ROWS_ 4096
#define CIN_ 288
#define COUT_ 128
#define NBKT 256
#define RMAX 81.0f

typedef unsigned long long u64;
typedef unsigned int u32;

// DPP wave64 reduction stages (VALU-only; result lands in lane 63).
#define DPP_MAXF(v, ctrl)                                                              \
  do {                                                                                 \
    int _s = __builtin_amdgcn_update_dpp(__float_as_int(v), __float_as_int(v), (ctrl), \
                                         0xF, 0xF, false);                             \
    (v) = fmaxf((v), __int_as_float(_s));                                              \
  } while (0)
#define DPP_MINU(v, ctrl)                                                              \
  do {                                                                                 \
    int _s = __builtin_amdgcn_update_dpp((int)(v), (int)(v), (ctrl), 0xF, 0xF, false); \
    (v) = ((u32)_s < (v)) ? (u32)_s : (v);                                             \
  } while (0)

// ---------------------------------------------------------------- FPS core (R13 verified)
// Scan -> mask+ctz -> MAXF chain -> scalar tie fast path (MINU fallback) ->
// lane0 key publish -> barrier -> key reduce -> coords by index.
// NW is semantics-free: slot p = tid + j*STRIDE enumerates the same compacted
// indices; key order (max d, min p) is over the same (d_p, p) pairs.
// R15 change: band 0 runs NW=8 (2 waves/SIMD) so latency segments of co-resident
// waves overlap instead of being fully exposed at 1 wave/SIMD.
template <int NW, int NL>
__device__ __forceinline__ void fps_core_lds(
    int tid, int lane, int wv, int M, int K, int base,
    const float* __restrict__ pts,
    const unsigned short* __restrict__ s_idx,
    float* __restrict__ s_x, float* __restrict__ s_y, float* __restrict__ s_z,
    u32* __restrict__ s_sel,
    u64 (* __restrict__ s_key)[16]) {
#pragma clang fp contract(off)
  constexpr int STRIDE = NW * 64;
  float lx[NL], ly[NL], lz[NL], ld[NL];
#pragma unroll
  for (int j = 0; j < NL; ++j) {
    int p = tid + j * STRIDE;
    bool v = p < M;
    int oi = v ? (int)s_idx[p] : 0;
    int gi = (base + oi) * 5;
    lx[j] = pts[gi + 1];
    ly[j] = pts[gi + 2];
    lz[j] = pts[gi + 3];
    ld[j] = v ? 1e10f : -1.0f;   // invalid slots pinned at -1: never selected
    s_x[p] = lx[j];
    s_y[p] = ly[j];
    s_z[p] = lz[j];
  }
  int gi0 = (base + (int)s_idx[0]) * 5;
  float lastx = pts[gi0 + 1], lasty = pts[gi0 + 2], lastz = pts[gi0 + 3];
  if (tid == 0) s_sel[0] = 0u;

  int bufc = 0;
  for (int k = 1; k < K; ++k) {
    float bd = -1.0f;
#pragma unroll
    for (int j = 0; j < NL; ++j) {
      float dx = lx[j] - lastx;
      float dy = ly[j] - lasty;
      float dz = lz[j] - lastz;
      float d = dx * dx;
      d += dy * dy;
      d += dz * dz;
      float nd = fminf(ld[j], d);
      ld[j] = nd;
      bd = fmaxf(bd, nd);
    }
    u32 m = 0u;
#pragma unroll
    for (int j = 0; j < NL; ++j) m |= (ld[j] == bd) ? (1u << j) : 0u;
    int bj = (int)__builtin_ctz(m);
    u32 bp = (u32)(tid + bj * STRIDE);

    float rd = bd;
    DPP_MAXF(rd, 0x111);
    DPP_MAXF(rd, 0x112);
    DPP_MAXF(rd, 0x114);
    DPP_MAXF(rd, 0x118);
    DPP_MAXF(rd, 0x142);
    DPP_MAXF(rd, 0x143);
    float maxd = __int_as_float(__builtin_amdgcn_readlane(__float_as_int(rd), 63));

    // ---- tie-break: scalar fast path (unique max-holder), exact MINU fallback
    u64 tie = __ballot(bd == maxd);
    u32 wp;
    if (__popcll(tie) == 1) {            // wave-uniform branch
      int wl = (int)__builtin_ctzll(tie);
      wp = (u32)__builtin_amdgcn_readlane((int)bp, wl);
    } else {
      u32 pc = (bd == maxd) ? bp : 0xFFFFFFFFu;
      u32 rp = pc;
      DPP_MINU(rp, 0x111);
      DPP_MINU(rp, 0x112);
      DPP_MINU(rp, 0x114);
      DPP_MINU(rp, 0x118);
      DPP_MINU(rp, 0x142);
      DPP_MINU(rp, 0x143);
      wp = (u32)__builtin_amdgcn_readlane((int)rp, 63);
    }

    if (lane == 0) {
      s_key[bufc][wv] = ((u64)__float_as_uint(maxd) << 32) | (u32)(~wp);
    }
    __syncthreads();
    u64 best = s_key[bufc][0];
#pragma unroll
    for (int w = 1; w < NW; ++w) {
      u64 cc = s_key[bufc][w];
      best = (cc > best) ? cc : best;
    }
    u32 pstar = ~(u32)best;
    lastx = s_x[pstar];
    lasty = s_y[pstar];
    lastz = s_z[pstar];
    if (tid == 0) s_sel[k] = pstar;
    bufc ^= 1;
  }
}

// ---------------------------------------------------------------- FPS core, round-0 fallback (M > 8192; not hit)
template <int NW, int NL>
__device__ __forceinline__ void fps_core_reg(
    int tid, int lane, int wv, int M, int K, int base,
    const float* __restrict__ pts,
    const unsigned short* __restrict__ s_idx,
    float4* __restrict__ s_k,
    u64 (* __restrict__ s_key)[16],
    float4 (* __restrict__ s_cxyz)[16]) {
#pragma clang fp contract(off)
  constexpr int STRIDE = NW * 64;
  float lx[NL], ly[NL], lz[NL], ld[NL];
#pragma unroll
  for (int j = 0; j < NL; ++j) {
    int p = tid + j * STRIDE;
    bool v = p < M;
    int oi = v ? (int)s_idx[p] : 0;
    int gi = (base + oi) * 5;
    lx[j] = pts[gi + 1];
    ly[j] = pts[gi + 2];
    lz[j] = pts[gi + 3];
    ld[j] = v ? 1e10f : -1.0f;
  }
  int gi0 = (base + (int)s_idx[0]) * 5;
  float lastx = pts[gi0 + 1], lasty = pts[gi0 + 2], lastz = pts[gi0 + 3];
  if (tid == 0) s_k[0] = make_float4(lastx, lasty, lastz, 0.f);
  __syncthreads();

  int bufc = 0;
  for (int k = 1; k < K; ++k) {
    float bd = -1.0f;
#pragma unroll
    for (int j = 0; j < NL; ++j) {
      float dx = lx[j] - lastx;
      float dy = ly[j] - lasty;
      float dz = lz[j] - lastz;
      float d = dx * dx;
      d += dy * dy;
      d += dz * dz;
      float nd = fminf(ld[j], d);
      ld[j] = nd;
      bd = fmaxf(bd, nd);
    }
    int bj = 0;
    float bx = lx[0], by = ly[0], bz = lz[0];
#pragma unroll
    for (int j = NL - 1; j >= 0; --j) {
      if (ld[j] == bd) { bj = j; bx = lx[j]; by = ly[j]; bz = lz[j]; }
    }
    int bp = tid + bj * STRIDE;

    float rd = bd;
    DPP_MAXF(rd, 0x111);
    DPP_MAXF(rd, 0x112);
    DPP_MAXF(rd, 0x114);
    DPP_MAXF(rd, 0x118);
    DPP_MAXF(rd, 0x142);
    DPP_MAXF(rd, 0x143);
    float maxd = __int_as_float(__builtin_amdgcn_readlane(__float_as_int(rd), 63));

    u32 pc = (bd == maxd) ? (u32)bp : 0xFFFFFFFFu;
    u32 rp = pc;
    DPP_MINU(rp, 0x111);
    DPP_MINU(rp, 0x112);
    DPP_MINU(rp, 0x114);
    DPP_MINU(rp, 0x118);
    DPP_MINU(rp, 0x142);
    DPP_MINU(rp, 0x143);
    u32 wp = (u32)__builtin_amdgcn_readlane((int)rp, 63);

    if (pc == wp) {
      s_key[bufc][wv] = ((u64)__float_as_uint(maxd) << 32) | (u32)(~wp);
      s_cxyz[bufc][wv] = make_float4(bx, by, bz, 0.f);
    }
    __syncthreads();
    u64 best = s_key[bufc][0];
#pragma unroll
    for (int w = 1; w < NW; ++w) {
      u64 cc = s_key[bufc][w];
      best = (cc > best) ? cc : best;
    }
    int cw = (int)((~(u32)best & (u32)(STRIDE - 1)) >> 6);
    float4 kk = s_cxyz[bufc][cw];
    lastx = kk.x; lasty = kk.y; lastz = kk.z;
    if (tid == 0) s_k[k] = kk;
    bufc ^= 1;
  }
}

// ---------------------------------------------------------------- FPS (0..5) + sf transpose (6..4405) + range sort (4406..4407)
__launch_bounds__(1024)
__global__ void k_fps(const float* __restrict__ pts, const float* __restrict__ rngv,
                      float* __restrict__ out2,
                      const float* __restrict__ sf, float* __restrict__ sfT,
                      float* __restrict__ sx, float* __restrict__ sy,
                      float* __restrict__ sz, float* __restrict__ sw,
                      u32* __restrict__ sid, u32* __restrict__ bst) {
#pragma clang fp contract(off)
  __shared__ unsigned short s_idx[NPTS_];          // 32 KB compacted -> original idx
  __shared__ __align__(16) float s_x[8192];        // 32 KB compacted coords (sel<=2)
  __shared__ float s_y[8192];                      // 32 KB
  __shared__ float s_z[8192];                      // 32 KB
  __shared__ u32 s_sel[1024];                      // 4 KB selected slots / sort hist
  __shared__ u64 s_key[2][16];
  __shared__ float4 s_cxyz[2][16];                 // fallback path only
  __shared__ int s_wsum[16];

  float4* s_k = reinterpret_cast<float4*>(s_x);    // fallback keypoint list overlays s_x

  const int tid = threadIdx.x, lane = tid & 63, wv = tid >> 6;

  if (blockIdx.x >= 6) {
    const int tb = (int)blockIdx.x - 6;
    if (tb < NB * 2200) {
      // ---------------- transpose path (tile 64 hw x 64 c, LDS overlays s_idx)
      float* tile = reinterpret_cast<float*>(s_idx);   // [64][65] = 16.6 KB
      const int b = tb / 2200;
      const int r = tb % 2200;
      const int hw0 = (r >> 2) * 64;
      const int c0 = (r & 3) * 64;
      const int cg = wv;
      const float* src = sf + (size_t)b * IMC * HW_;
#pragma unroll
      for (int j = 0; j < 4; ++j) {
        int cl = cg * 4 + j;
        tile[cl * 65 + lane] = src[(size_t)(c0 + cl) * HW_ + hw0 + lane];
      }
      __syncthreads();
      float* dst = sfT + (size_t)b * HW_ * IMC;
#pragma unroll
      for (int j = 0; j < 4; ++j) {
        int hwl = cg * 4 + j;
        dst[(size_t)(hw0 + hwl) * IMC + c0 + lane] = tile[lane * 65 + hwl];
      }
      return;
    }
    // ---------------- range counting sort path (1 block per batch)
    const int b = tb - NB * 2200;
    const float INV = (float)NBKT / RMAX;
    u32* hist = s_sel;   // 256 bins
    if (tid < NBKT) hist[tid] = 0u;
    __syncthreads();
    for (int j = 0; j < 16; ++j) {
      int i = tid * 16 + j;
      float r = rngv[b * NPTS_ + i];
      int bin = min(NBKT - 1, max(0, (int)(r * INV)));
      atomicAdd(&hist[bin], 1u);
    }
    __syncthreads();
    if (tid < 64) {
      int c0 = hist[tid * 4], c1 = hist[tid * 4 + 1];
      int c2 = hist[tid * 4 + 2], c3 = hist[tid * 4 + 3];
      int s = c0 + c1 + c2 + c3;
      for (int d = 1; d < 64; d <<= 1) {
        int o = __shfl_up(s, d);
        if (lane >= d) s += o;
      }
      int b0 = s - (c0 + c1 + c2 + c3);
      hist[tid * 4] = b0;
      hist[tid * 4 + 1] = b0 + c0;
      hist[tid * 4 + 2] = b0 + c0 + c1;
      hist[tid * 4 + 3] = b0 + c0 + c1 + c2;
    }
    __syncthreads();
    if (tid < NBKT) bst[b * (NBKT + 1) + tid] = hist[tid];
    if (tid == 0) bst[b * (NBKT + 1) + NBKT] = NPTS_;
    __syncthreads();   // bst reads of hist done before scatter mutates it
    for (int j = 0; j < 16; ++j) {
      int i = tid * 16 + j;
      float r = rngv[b * NPTS_ + i];
      int bin = min(NBKT - 1, max(0, (int)(r * INV)));
      u32 pos = atomicAdd(&hist[bin], 1u);
      int gi = (b * NPTS_ + i) * 5;
      size_t o = (size_t)b * NPTS_ + pos;
      sx[o] = pts[gi + 1];
      sy[o] = pts[gi + 2];
      sz[o] = pts[gi + 3];
      sw[o] = pts[gi + 4];
      sid[o] = (u32)i;
    }
    return;
  }

  // ---------------- FPS path (blocks 0..5)
  const int blk = blockIdx.x;
  const int band = blk % 3, batch = blk / 3;
  const int K = (band == 0) ? 1024 : 512;
  const int off = (band == 0) ? 0 : (band == 1 ? 1024 : 1536);
  const int base = batch * NPTS_;

  unsigned int vm = 0u;
  for (int j = 0; j < 16; ++j) {
    float r = rngv[base + tid * 16 + j];
    bool sm = (r > 0.0f) && (r < 25.0f);
    bool lm = (r > 45.0f);
    bool v = (band == 0) ? sm : (band == 2 ? lm : (!lm && !sm));
    vm |= (v ? 1u : 0u) << j;
  }
  int cnt = __popc(vm);
  int inc = cnt;
  for (int d = 1; d < 64; d <<= 1) {
    int o = __shfl_up(inc, d);
    if (lane >= d) inc += o;
  }
  if (lane == 63) s_wsum[wv] = inc;
  __syncthreads();
  int woff = 0, M = 0;
  for (int w = 0; w < 16; ++w) {
    if (w < wv) woff += s_wsum[w];
    M += s_wsum[w];
  }
  int myoff = woff + inc - cnt;
  unsigned int t = vm;
  while (t) {
    int b = __builtin_ctz(t);
    t &= t - 1;
    s_idx[myoff++] = (unsigned short)(tid * 16 + b);
  }
  __syncthreads();

  // ---- band/M-dependent core: 8 waves for all sel<=2 (2 waves/SIMD latency overlap)
  int sel;  // 0:(8,6) 1:(8,8) 2:(8,16) 3:(16,16)
  if (band == 0) {
    if (M <= 3072) sel = 0;
    else if (M <= 4096) sel = 1;
    else if (M <= 8192) sel = 2;
    else sel = 3;
  } else {
    sel = (M <= 8192) ? 2 : 3;
  }
  const int nw = (sel <= 2) ? 8 : 16;
  if (tid >= nw * 64) return;

  if (sel == 0)      fps_core_lds<8, 6>(tid, lane, wv, M, K, base, pts, s_idx, s_x, s_y, s_z, s_sel, s_key);
  else if (sel == 1) fps_core_lds<8, 8>(tid, lane, wv, M, K, base, pts, s_idx, s_x, s_y, s_z, s_sel, s_key);
  else if (sel == 2) fps_core_lds<8, 16>(tid, lane, wv, M, K, base, pts, s_idx, s_x, s_y, s_z, s_sel, s_key);
  else               fps_core_reg<16, 16>(tid, lane, wv, M, K, base, pts, s_idx, s_k, s_key, s_cxyz);

  __syncthreads();
  const float batf = (float)batch;
  if (sel <= 2) {
    for (int i = tid; i < K; i += nw * 64) {
      int g = (batch * KTOT_ + off + i) * 4;
      u32 p = s_sel[i];
      out2[g + 0] = batf;
      out2[g + 1] = s_x[p];
      out2[g + 2] = s_y[p];
      out2[g + 3] = s_z[p];
    }
  } else {
    for (int i = tid; i < K; i += nw * 64) {
      int g = (batch * KTOT_ + off + i) * 4;
      float4 kk = s_k[i];
      out2[g + 0] = batf;
      out2[g + 1] = kk.x;
      out2[g + 2] = kk.y;
      out2[g + 3] = kk.z;
    }
  }
}

// ---------------------------------------------------------------- BEV + SA + fusion, one block per 4 rows
// (Byte-identical to the verified R14 kernel.)
__launch_bounds__(256)
__global__ void k_bsf(const float* __restrict__ sf, const float* __restrict__ sfT, int doT,
                      const float* __restrict__ out2, const float* __restrict__ pts,
                      const float* __restrict__ w0, const float* __restrict__ bn0,
                      const float* __restrict__ w1, const float* __restrict__ bn1,
                      const float* __restrict__ fw, const float* __restrict__ fbn,
                      const float* __restrict__ sx, const float* __restrict__ sy,
                      const float* __restrict__ sz, const float* __restrict__ sw,
                      const u32* __restrict__ sid, const u32* __restrict__ bst,
                      float* __restrict__ out1, float* __restrict__ out0) {
#pragma clang fp contract(off)
  __shared__ float s_w0[128];
  __shared__ float s_w1[512];
  __shared__ float s_s0[32], s_m0[32], s_b0[32];
  __shared__ float s_s1[32], s_m1[32], s_b1[32];
  __shared__ float4 s_nb[4][2][16];
  __shared__ float s_row[4][CIN_];
  __shared__ u32 s_li[4][128];                     // hit idx | flag<<31
  __shared__ __align__(16) float4 s_ldt[4][128];   // hit (p-k, feat)

  int tid = threadIdx.x, lane = tid & 63, wv = tid >> 6;

  for (int i = tid; i < 128; i += 256) s_w0[i] = w0[i];
  for (int i = tid; i < 512; i += 256) s_w1[i] = w1[i];
  if (tid < 32) {
    int rad = tid >> 4, c = tid & 15;
    int bb = rad * 64;
    {
      float gg = bn0[bb + c], bbt = bn0[bb + 16 + c];
      float mm = bn0[bb + 32 + c], vv = bn0[bb + 48 + c];
      s_s0[tid] = gg / sqrtf(vv + 1e-5f); s_m0[tid] = mm; s_b0[tid] = bbt;
    }
    {
      float gg = bn1[bb + c], bbt = bn1[bb + 16 + c];
      float mm = bn1[bb + 32 + c], vv = bn1[bb + 48 + c];
      s_s1[tid] = gg / sqrtf(vv + 1e-5f); s_m1[tid] = mm; s_b1[tid] = bbt;
    }
  }
  __syncthreads();

  int g = blockIdx.x * 4 + wv;
  int batch = g >> 11;
  int base = batch * NPTS_;
  float kx = out2[g * 4 + 1];
  float ky = out2[g * 4 + 2];
  float kz = out2[g * 4 + 3];

  // ---------------- BEV
  {
    float x = (kx - 0.0f) / 0.05f / 8.0f;
    float y = (ky - (-40.0f)) / 0.05f / 8.0f;
    int x0 = (int)floorf(x), y0 = (int)floorf(y);
    int x1 = x0 + 1, y1 = y0 + 1;
    x0 = min(max(x0, 0), IMW - 1); x1 = min(max(x1, 0), IMW - 1);
    y0 = min(max(y0, 0), IMH - 1); y1 = min(max(y1, 0), IMH - 1);
    float x0f = (float)x0, x1f = (float)x1, y0f = (float)y0, y1f = (float)y1;
    float wa = (x1f - x) * (y1f - y);
    float wb = (x1f - x) * (y - y0f);
    float wc = (x - x0f) * (y1f - y);
    float wd = (x - x0f) * (y - y0f);
    int oa = y0 * IMW + x0;
    int ob = y1 * IMW + x0;
    int oc = y0 * IMW + x1;
    int od = y1 * IMW + x1;
    if (doT) {
      const float* pb = sfT + (size_t)batch * HW_ * IMC;
      const float4* va = (const float4*)(pb + (size_t)oa * IMC) + lane;
      const float4* vb = (const float4*)(pb + (size_t)ob * IMC) + lane;
      const float4* vc = (const float4*)(pb + (size_t)oc * IMC) + lane;
      const float4* vd = (const float4*)(pb + (size_t)od * IMC) + lane;
      float4 A = *va, B = *vb, C = *vc, D = *vd;
      float4 o;
      o.x = A.x * wa; o.x += B.x * wb; o.x += C.x * wc; o.x += D.x * wd;
      o.y = A.y * wa; o.y += B.y * wb; o.y += C.y * wc; o.y += D.y * wd;
      o.z = A.z * wa; o.z += B.z * wb; o.z += C.z * wc; o.z += D.z * wd;
      o.w = A.w * wa; o.w += B.w * wb; o.w += C.w * wc; o.w += D.w * wd;
      *(float4*)&out1[(size_t)g * CIN_ + lane * 4] = o;
      *(float4*)&s_row[wv][lane * 4] = o;
    } else {
      const float* pb = sf + (size_t)batch * IMC * HW_;
      for (int j = 0; j < 4; ++j) {
        int c = lane * 4 + j;
        const float* pc = pb + (size_t)c * HW_;
        float o = pc[oa] * wa;
        o += pc[ob] * wb;
        o += pc[oc] * wc;
        o += pc[od] * wd;
        out1[(size_t)g * CIN_ + c] = o;
        s_row[wv][c] = o;
      }
    }
  }

  // ---------------- SA
  int c1 = 0, c2 = 0;
  bool fast = false;
  if (doT) {
    const float INV = (float)NBKT / RMAX;
    float rk = sqrtf(kx * kx + ky * ky);
    int blo = max(0, (int)((rk - 2.001f) * INV));
    int bhi = min(NBKT - 1, (int)((rk + 2.001f) * INV));
    const u32* bb = bst + batch * (NBKT + 1);
    int S0 = (int)bb[blo], S1 = (int)bb[bhi + 1];
    const float* SX = sx + (size_t)batch * NPTS_;
    const float* SY = sy + (size_t)batch * NPTS_;
    const float* SZ = sz + (size_t)batch * NPTS_;
    const float* SW = sw + (size_t)batch * NPTS_;
    const u32* SI = sid + (size_t)batch * NPTS_;
    for (int s0 = S0; s0 < S1; s0 += 64) {
      int sl = s0 + lane;
      bool vld = sl < S1;
      int slc = vld ? sl : S0;
      float px = SX[slc], py = SY[slc], pz = SZ[slc], pw = SW[slc];
      u32 pid = SI[slc];
      float dx = kx - px;
      float dy = ky - py;
      float dz = kz - pz;
      float d = dx * dx;
      d += dy * dy;
      d += dz * dz;
      bool h1 = vld && (d < 1.0f);
      bool h2 = vld && (d < 4.0f);
      u64 m2 = __ballot(h2);
      int below = __builtin_amdgcn_mbcnt_hi((u32)(m2 >> 32),
                    __builtin_amdgcn_mbcnt_lo((u32)m2, 0));
      int rank = c2 + below;
      if (h2 && rank < 128) {
        s_li[wv][rank] = pid | (h1 ? 0x80000000u : 0u);
        s_ldt[wv][rank] = make_float4(-dx, -dy, -dz, pw);   // -dx == px-kx bit-exact
      }
      c2 += __popcll(m2);
      c1 += __popcll(__ballot(h1));
    }
    fast = (c2 <= 128);
    if (fast) {
      // ---- rank-based scatter (identical output to serial min-extract)
      int n = c2;
      const u32 BIG = 0x7FFFFFFFu;
      u32 e0 = (lane < n) ? s_li[wv][lane] : 0xFFFFFFFFu;
      u32 e1 = (lane + 64 < n) ? s_li[wv][lane + 64] : 0xFFFFFFFFu;
      bool v0 = (e0 != 0xFFFFFFFFu), v1 = (e1 != 0xFFFFFFFFu);
      bool f0 = v0 && (e0 & 0x80000000u), f1 = v1 && (e1 & 0x80000000u);
      u32 i0 = e0 & BIG, i1 = e1 & BIG;
      int r0a = 0, r0b = 0, r1a = 0, r1b = 0;
      for (int j = 0; j < n; ++j) {
        u32 vj = s_li[wv][j];          // broadcast LDS read (all lanes same addr)
        u32 ij = vj & BIG;
        bool fj = (vj & 0x80000000u) != 0u;
        bool l0 = ij < i0;
        bool l1 = ij < i1;
        r0b += l0 ? 1 : 0;
        r1b += l1 ? 1 : 0;
        r0a += (fj && l0) ? 1 : 0;
        r1a += (fj && l1) ? 1 : 0;
      }
      if (f0 && r0a < 16) s_nb[wv][0][r0a] = s_ldt[wv][lane];
      if (f1 && r1a < 16) s_nb[wv][0][r1a] = s_ldt[wv][lane + 64];
      if (v0 && r0b < 16) s_nb[wv][1][r0b] = s_ldt[wv][lane];
      if (v1 && r1b < 16) s_nb[wv][1][r1b] = s_ldt[wv][lane + 64];
    }
  }
  if (!fast) {
    // full index-order scan (fallback / !doT) — verified R5 logic
    c1 = 0; c2 = 0;
    for (int r = 0; r < NPTS_ / 64; ++r) {
      int gi = (base + r * 64 + lane) * 5;
      float px = pts[gi + 1];
      float py = pts[gi + 2];
      float pz = pts[gi + 3];
      float pw = pts[gi + 4];
      float dx = kx - px;
      float dy = ky - py;
      float dz = kz - pz;
      float d = dx * dx;
      d += dy * dy;
      d += dz * dz;
      bool h1 = d < 1.0f;
      bool h2 = d < 4.0f;
      u64 m1 = __ballot(h1);
      u64 m2 = __ballot(h2);
      int below1 = __builtin_amdgcn_mbcnt_hi((u32)(m1 >> 32),
                    __builtin_amdgcn_mbcnt_lo((u32)m1, 0));
      int below2 = __builtin_amdgcn_mbcnt_hi((u32)(m2 >> 32),
                    __builtin_amdgcn_mbcnt_lo((u32)m2, 0));
      int rank1 = c1 + below1;
      int rank2 = c2 + below2;
      if (h1 && rank1 < 16) s_nb[wv][0][rank1] = make_float4(px - kx, py - ky, pz - kz, pw);
      if (h2 && rank2 < 16) s_nb[wv][1][rank2] = make_float4(px - kx, py - ky, pz - kz, pw);
      c1 += __popcll(m1);
      c2 += __popcll(m2);
      if (c1 >= 16 && c2 >= 16) break;
    }
  }

  int myrad = (lane >> 4) & 1, myslot = lane & 15;
  int cnt = (myrad == 0) ? min(c1, 16) : min(c2, 16);
  float gx = 0.f, gy = 0.f, gz = 0.f, gf = 0.f;
  if (lane < 32 && cnt > 0) {
    int src = (myslot < cnt) ? myslot : 0;
    float4 nb = s_nb[wv][myrad][src];
    gx = nb.x; gy = nb.y; gz = nb.z; gf = nb.w;
  }
  const float* W0 = s_w0 + myrad * 64;
  const float* W1 = s_w1 + myrad * 256;
  int bc = myrad * 16;
  float h1v[16];
  for (int c = 0; c < 16; ++c) {
    float a = gx * W0[c];
    a += gy * W0[16 + c];
    a += gz * W0[32 + c];
    a += gf * W0[48 + c];
    h1v[c] = fmaxf((a - s_m0[bc + c]) * s_s0[bc + c] + s_b0[bc + c], 0.f);
  }
  for (int c = 0; c < 16; ++c) {
    float a = 0.f;
    for (int k = 0; k < 16; ++k) a += h1v[k] * W1[k * 16 + c];
    float h2v = fmaxf((a - s_m1[bc + c]) * s_s1[bc + c] + s_b1[bc + c], 0.f);
    h2v = fmaxf(h2v, __shfl_xor(h2v, 1));
    h2v = fmaxf(h2v, __shfl_xor(h2v, 2));
    h2v = fmaxf(h2v, __shfl_xor(h2v, 4));
    h2v = fmaxf(h2v, __shfl_xor(h2v, 8));
    if (lane < 32 && myslot == 0) {
      int col = 256 + myrad * 16 + c;
      out1[(size_t)g * CIN_ + col] = h2v;
      s_row[wv][col] = h2v;
    }
  }

  // ---------------- fusion
  __syncthreads();
  {
    int col = tid & 127, rh = tid >> 7;
    float a0 = 0.f, a1 = 0.f;
    for (int k = 0; k < CIN_; ++k) {
      float w = fw[k * COUT_ + col];
      a0 += s_row[rh][k] * w;
      a1 += s_row[rh + 2][k] * w;
    }
    float gg = fbn[col], bb = fbn[COUT_ + col];
    float mm = fbn[2 * COUT_ + col], vv = fbn[3 * COUT_ + col];
    float sc = gg / sqrtf(vv + 1e-5f);
    int g0 = blockIdx.x * 4;
    out0[(size_t)(g0 + rh) * COUT_ + col] = fmaxf((a0 - mm) * sc + bb, 0.f);
    out0[(size_t)(g0 + rh + 2) * COUT_ + col] = fmaxf((a1 - mm) * sc + bb, 0.f);
  }
}

// ---------------------------------------------------------------- launch
extern "C" void kernel_launch(void* const* d_in, const int* in_sizes, int n_in,
                              void* d_out, int out_size, void* d_ws, size_t ws_size,
                              hipStream_t stream) {
  const float* points = (const float*)d_in[0];
  const float* rng    = (const float*)d_in[1];
  const float* sf     = (const float*)d_in[2];
  const float* w0     = (const float*)d_in[3];
  const float* bn0    = (const float*)d_in[4];
  const float* w1     = (const float*)d_in[5];
  const float* bn1    = (const float*)d_in[6];
  const float* fw     = (const float*)d_in[7];
  const float* fbn    = (const float*)d_in[8];

  float* out0 = (float*)d_out;                         // fused [4096,128]
  float* out1 = out0 + (size_t)ROWS_ * COUT_;          // feats [4096,288]
  float* out2 = out1 + (size_t)ROWS_ * CIN_;           // point_coords [4096,4]

  const size_t SFT_CNT = (size_t)NB * IMC * HW_;       // floats
  const size_t SORT_CNT = (size_t)NB * NPTS_;          // per array
  const size_t need = (SFT_CNT + 5 * SORT_CNT + NB * (NBKT + 1)) * 4;
  const int doT = (d_ws != nullptr && ws_size >= need) ? 1 : 0;
  float* sfT = (float*)d_ws;
  float* sx = sfT + SFT_CNT;
  float* sy = sx + SORT_CNT;
  float* sz = sy + SORT_CNT;
  float* sw = sz + SORT_CNT;
  u32* sid = (u32*)(sw + SORT_CNT);
  u32* bst = sid + SORT_CNT;

  // blocks 0..5 FPS; 6..4405 transpose; 4406..4407 range sort (all hidden under FPS)
  k_fps<<<doT ? (6 + NB * 2200 + NB) : 6, 1024, 0, stream>>>(
      points, rng, out2, sf, sfT, sx, sy, sz, sw, sid, bst);
  k_bsf<<<ROWS_ / 4, 256, 0, stream>>>(sf, sfT, doT, out2, points, w0, bn0, w1, bn1,
                                       fw, fbn, sx, sy, sz, sw, sid, bst, out1, out0);
}

// Round 16
// 760.084 us; speedup vs baseline: 1.2065x; 1.2065x over previous
//
#include <hip/hip_runtime.h>
#include <hip/hip_bf16.h>
#include <climits>

#define NB 2
#define NPTS_ 16384
#define IMH 200
#define IMW 176
#define IMC 256
#define HW_ (IMH * IMW)
#define KTOT_ 2048
#define ROWS_ 4096
#define CIN_ 288
#define COUT_ 128
#define NBKT 256
#define RMAX 81.0f

typedef unsigned long long u64;
typedef unsigned int u32;

// DPP wave64 reduction stages (VALU-only; result lands in lane 63).
#define DPP_MAXF(v, ctrl)                                                              \
  do {                                                                                 \
    int _s = __builtin_amdgcn_update_dpp(__float_as_int(v), __float_as_int(v), (ctrl), \
                                         0xF, 0xF, false);                             \
    (v) = fmaxf((v), __int_as_float(_s));                                              \
  } while (0)
#define DPP_MINU(v, ctrl)                                                              \
  do {                                                                                 \
    int _s = __builtin_amdgcn_update_dpp((int)(v), (int)(v), (ctrl), 0xF, 0xF, false); \
    (v) = ((u32)_s < (v)) ? (u32)_s : (v);                                             \
  } while (0)

// ---------------------------------------------------------------- FPS core (R13 verified, 634us)
// Scan -> mask+ctz -> MAXF chain -> scalar tie fast path (MINU fallback) ->
// lane0 key publish -> barrier -> key reduce -> coords by index.
// Wave-count response fully mapped (R7/R15/ladder): 4 waves @ 1 wave/SIMD optimal
// for small M — issue-sharing between co-resident waves stretches the serial chain.
template <int NW, int NL>
__device__ __forceinline__ void fps_core_lds(
    int tid, int lane, int wv, int M, int K, int base,
    const float* __restrict__ pts,
    const unsigned short* __restrict__ s_idx,
    float* __restrict__ s_x, float* __restrict__ s_y, float* __restrict__ s_z,
    u32* __restrict__ s_sel,
    u64 (* __restrict__ s_key)[16]) {
#pragma clang fp contract(off)
  constexpr int STRIDE = NW * 64;
  float lx[NL], ly[NL], lz[NL], ld[NL];
#pragma unroll
  for (int j = 0; j < NL; ++j) {
    int p = tid + j * STRIDE;
    bool v = p < M;
    int oi = v ? (int)s_idx[p] : 0;
    int gi = (base + oi) * 5;
    lx[j] = pts[gi + 1];
    ly[j] = pts[gi + 2];
    lz[j] = pts[gi + 3];
    ld[j] = v ? 1e10f : -1.0f;   // invalid slots pinned at -1: never selected
    s_x[p] = lx[j];
    s_y[p] = ly[j];
    s_z[p] = lz[j];
  }
  int gi0 = (base + (int)s_idx[0]) * 5;
  float lastx = pts[gi0 + 1], lasty = pts[gi0 + 2], lastz = pts[gi0 + 3];
  if (tid == 0) s_sel[0] = 0u;

  int bufc = 0;
  for (int k = 1; k < K; ++k) {
    float bd = -1.0f;
#pragma unroll
    for (int j = 0; j < NL; ++j) {
      float dx = lx[j] - lastx;
      float dy = ly[j] - lasty;
      float dz = lz[j] - lastz;
      float d = dx * dx;
      d += dy * dy;
      d += dz * dz;
      float nd = fminf(ld[j], d);
      ld[j] = nd;
      bd = fmaxf(bd, nd);
    }
    u32 m = 0u;
#pragma unroll
    for (int j = 0; j < NL; ++j) m |= (ld[j] == bd) ? (1u << j) : 0u;
    int bj = (int)__builtin_ctz(m);
    u32 bp = (u32)(tid + bj * STRIDE);

    float rd = bd;
    DPP_MAXF(rd, 0x111);
    DPP_MAXF(rd, 0x112);
    DPP_MAXF(rd, 0x114);
    DPP_MAXF(rd, 0x118);
    DPP_MAXF(rd, 0x142);
    DPP_MAXF(rd, 0x143);
    float maxd = __int_as_float(__builtin_amdgcn_readlane(__float_as_int(rd), 63));

    // ---- tie-break: scalar fast path (unique max-holder), exact MINU fallback
    u64 tie = __ballot(bd == maxd);
    u32 wp;
    if (__popcll(tie) == 1) {            // wave-uniform branch
      int wl = (int)__builtin_ctzll(tie);
      wp = (u32)__builtin_amdgcn_readlane((int)bp, wl);
    } else {
      u32 pc = (bd == maxd) ? bp : 0xFFFFFFFFu;
      u32 rp = pc;
      DPP_MINU(rp, 0x111);
      DPP_MINU(rp, 0x112);
      DPP_MINU(rp, 0x114);
      DPP_MINU(rp, 0x118);
      DPP_MINU(rp, 0x142);
      DPP_MINU(rp, 0x143);
      wp = (u32)__builtin_amdgcn_readlane((int)rp, 63);
    }

    if (lane == 0) {
      s_key[bufc][wv] = ((u64)__float_as_uint(maxd) << 32) | (u32)(~wp);
    }
    __syncthreads();
    u64 best = s_key[bufc][0];
#pragma unroll
    for (int w = 1; w < NW; ++w) {
      u64 cc = s_key[bufc][w];
      best = (cc > best) ? cc : best;
    }
    u32 pstar = ~(u32)best;
    lastx = s_x[pstar];
    lasty = s_y[pstar];
    lastz = s_z[pstar];
    if (tid == 0) s_sel[k] = pstar;
    bufc ^= 1;
  }
}

// ---------------------------------------------------------------- FPS core, round-0 fallback (M > 8192; not hit)
template <int NW, int NL>
__device__ __forceinline__ void fps_core_reg(
    int tid, int lane, int wv, int M, int K, int base,
    const float* __restrict__ pts,
    const unsigned short* __restrict__ s_idx,
    float4* __restrict__ s_k,
    u64 (* __restrict__ s_key)[16],
    float4 (* __restrict__ s_cxyz)[16]) {
#pragma clang fp contract(off)
  constexpr int STRIDE = NW * 64;
  float lx[NL], ly[NL], lz[NL], ld[NL];
#pragma unroll
  for (int j = 0; j < NL; ++j) {
    int p = tid + j * STRIDE;
    bool v = p < M;
    int oi = v ? (int)s_idx[p] : 0;
    int gi = (base + oi) * 5;
    lx[j] = pts[gi + 1];
    ly[j] = pts[gi + 2];
    lz[j] = pts[gi + 3];
    ld[j] = v ? 1e10f : -1.0f;
  }
  int gi0 = (base + (int)s_idx[0]) * 5;
  float lastx = pts[gi0 + 1], lasty = pts[gi0 + 2], lastz = pts[gi0 + 3];
  if (tid == 0) s_k[0] = make_float4(lastx, lasty, lastz, 0.f);
  __syncthreads();

  int bufc = 0;
  for (int k = 1; k < K; ++k) {
    float bd = -1.0f;
#pragma unroll
    for (int j = 0; j < NL; ++j) {
      float dx = lx[j] - lastx;
      float dy = ly[j] - lasty;
      float dz = lz[j] - lastz;
      float d = dx * dx;
      d += dy * dy;
      d += dz * dz;
      float nd = fminf(ld[j], d);
      ld[j] = nd;
      bd = fmaxf(bd, nd);
    }
    int bj = 0;
    float bx = lx[0], by = ly[0], bz = lz[0];
#pragma unroll
    for (int j = NL - 1; j >= 0; --j) {
      if (ld[j] == bd) { bj = j; bx = lx[j]; by = ly[j]; bz = lz[j]; }
    }
    int bp = tid + bj * STRIDE;

    float rd = bd;
    DPP_MAXF(rd, 0x111);
    DPP_MAXF(rd, 0x112);
    DPP_MAXF(rd, 0x114);
    DPP_MAXF(rd, 0x118);
    DPP_MAXF(rd, 0x142);
    DPP_MAXF(rd, 0x143);
    float maxd = __int_as_float(__builtin_amdgcn_readlane(__float_as_int(rd), 63));

    u32 pc = (bd == maxd) ? (u32)bp : 0xFFFFFFFFu;
    u32 rp = pc;
    DPP_MINU(rp, 0x111);
    DPP_MINU(rp, 0x112);
    DPP_MINU(rp, 0x114);
    DPP_MINU(rp, 0x118);
    DPP_MINU(rp, 0x142);
    DPP_MINU(rp, 0x143);
    u32 wp = (u32)__builtin_amdgcn_readlane((int)rp, 63);

    if (pc == wp) {
      s_key[bufc][wv] = ((u64)__float_as_uint(maxd) << 32) | (u32)(~wp);
      s_cxyz[bufc][wv] = make_float4(bx, by, bz, 0.f);
    }
    __syncthreads();
    u64 best = s_key[bufc][0];
#pragma unroll
    for (int w = 1; w < NW; ++w) {
      u64 cc = s_key[bufc][w];
      best = (cc > best) ? cc : best;
    }
    int cw = (int)((~(u32)best & (u32)(STRIDE - 1)) >> 6);
    float4 kk = s_cxyz[bufc][cw];
    lastx = kk.x; lasty = kk.y; lastz = kk.z;
    if (tid == 0) s_k[k] = kk;
    bufc ^= 1;
  }
}

// ---------------------------------------------------------------- FPS (0..5) + sf transpose (6..4405) + range sort (4406..4407)
__launch_bounds__(1024)
__global__ void k_fps(const float* __restrict__ pts, const float* __restrict__ rngv,
                      float* __restrict__ out2,
                      const float* __restrict__ sf, float* __restrict__ sfT,
                      float* __restrict__ sx, float* __restrict__ sy,
                      float* __restrict__ sz, float* __restrict__ sw,
                      u32* __restrict__ sid, u32* __restrict__ bst) {
#pragma clang fp contract(off)
  __shared__ unsigned short s_idx[NPTS_];          // 32 KB compacted -> original idx
  __shared__ __align__(16) float s_x[8192];        // 32 KB compacted coords (sel<=2)
  __shared__ float s_y[8192];                      // 32 KB
  __shared__ float s_z[8192];                      // 32 KB
  __shared__ u32 s_sel[1024];                      // 4 KB selected slots / sort hist
  __shared__ u64 s_key[2][16];
  __shared__ float4 s_cxyz[2][16];                 // fallback path only
  __shared__ int s_wsum[16];

  float4* s_k = reinterpret_cast<float4*>(s_x);    // fallback keypoint list overlays s_x

  const int tid = threadIdx.x, lane = tid & 63, wv = tid >> 6;

  if (blockIdx.x >= 6) {
    const int tb = (int)blockIdx.x - 6;
    if (tb < NB * 2200) {
      // ---------------- transpose path (tile 64 hw x 64 c, LDS overlays s_idx)
      float* tile = reinterpret_cast<float*>(s_idx);   // [64][65] = 16.6 KB
      const int b = tb / 2200;
      const int r = tb % 2200;
      const int hw0 = (r >> 2) * 64;
      const int c0 = (r & 3) * 64;
      const int cg = wv;
      const float* src = sf + (size_t)b * IMC * HW_;
#pragma unroll
      for (int j = 0; j < 4; ++j) {
        int cl = cg * 4 + j;
        tile[cl * 65 + lane] = src[(size_t)(c0 + cl) * HW_ + hw0 + lane];
      }
      __syncthreads();
      float* dst = sfT + (size_t)b * HW_ * IMC;
#pragma unroll
      for (int j = 0; j < 4; ++j) {
        int hwl = cg * 4 + j;
        dst[(size_t)(hw0 + hwl) * IMC + c0 + lane] = tile[lane * 65 + hwl];
      }
      return;
    }
    // ---------------- range counting sort path (1 block per batch)
    const int b = tb - NB * 2200;
    const float INV = (float)NBKT / RMAX;
    u32* hist = s_sel;   // 256 bins
    if (tid < NBKT) hist[tid] = 0u;
    __syncthreads();
    for (int j = 0; j < 16; ++j) {
      int i = tid * 16 + j;
      float r = rngv[b * NPTS_ + i];
      int bin = min(NBKT - 1, max(0, (int)(r * INV)));
      atomicAdd(&hist[bin], 1u);
    }
    __syncthreads();
    if (tid < 64) {
      int c0 = hist[tid * 4], c1 = hist[tid * 4 + 1];
      int c2 = hist[tid * 4 + 2], c3 = hist[tid * 4 + 3];
      int s = c0 + c1 + c2 + c3;
      for (int d = 1; d < 64; d <<= 1) {
        int o = __shfl_up(s, d);
        if (lane >= d) s += o;
      }
      int b0 = s - (c0 + c1 + c2 + c3);
      hist[tid * 4] = b0;
      hist[tid * 4 + 1] = b0 + c0;
      hist[tid * 4 + 2] = b0 + c0 + c1;
      hist[tid * 4 + 3] = b0 + c0 + c1 + c2;
    }
    __syncthreads();
    if (tid < NBKT) bst[b * (NBKT + 1) + tid] = hist[tid];
    if (tid == 0) bst[b * (NBKT + 1) + NBKT] = NPTS_;
    __syncthreads();   // bst reads of hist done before scatter mutates it
    for (int j = 0; j < 16; ++j) {
      int i = tid * 16 + j;
      float r = rngv[b * NPTS_ + i];
      int bin = min(NBKT - 1, max(0, (int)(r * INV)));
      u32 pos = atomicAdd(&hist[bin], 1u);
      int gi = (b * NPTS_ + i) * 5;
      size_t o = (size_t)b * NPTS_ + pos;
      sx[o] = pts[gi + 1];
      sy[o] = pts[gi + 2];
      sz[o] = pts[gi + 3];
      sw[o] = pts[gi + 4];
      sid[o] = (u32)i;
    }
    return;
  }

  // ---------------- FPS path (blocks 0..5)
  const int blk = blockIdx.x;
  const int band = blk % 3, batch = blk / 3;
  const int K = (band == 0) ? 1024 : 512;
  const int off = (band == 0) ? 0 : (band == 1 ? 1024 : 1536);
  const int base = batch * NPTS_;

  unsigned int vm = 0u;
  for (int j = 0; j < 16; ++j) {
    float r = rngv[base + tid * 16 + j];
    bool sm = (r > 0.0f) && (r < 25.0f);
    bool lm = (r > 45.0f);
    bool v = (band == 0) ? sm : (band == 2 ? lm : (!lm && !sm));
    vm |= (v ? 1u : 0u) << j;
  }
  int cnt = __popc(vm);
  int inc = cnt;
  for (int d = 1; d < 64; d <<= 1) {
    int o = __shfl_up(inc, d);
    if (lane >= d) inc += o;
  }
  if (lane == 63) s_wsum[wv] = inc;
  __syncthreads();
  int woff = 0, M = 0;
  for (int w = 0; w < 16; ++w) {
    if (w < wv) woff += s_wsum[w];
    M += s_wsum[w];
  }
  int myoff = woff + inc - cnt;
  unsigned int t = vm;
  while (t) {
    int b = __builtin_ctz(t);
    t &= t - 1;
    s_idx[myoff++] = (unsigned short)(tid * 16 + b);
  }
  __syncthreads();

  int sel;  // 0:(4,12) 1:(4,16) 2:(8,16) 3:(16,16)
  if (band == 0) {
    if (M <= 3072) sel = 0;
    else if (M <= 4096) sel = 1;
    else if (M <= 8192) sel = 2;
    else sel = 3;
  } else {
    sel = (M <= 8192) ? 2 : 3;
  }
  const int nw = (sel <= 1) ? 4 : (sel == 2 ? 8 : 16);
  if (tid >= nw * 64) return;

  if (sel == 0)      fps_core_lds<4, 12>(tid, lane, wv, M, K, base, pts, s_idx, s_x, s_y, s_z, s_sel, s_key);
  else if (sel == 1) fps_core_lds<4, 16>(tid, lane, wv, M, K, base, pts, s_idx, s_x, s_y, s_z, s_sel, s_key);
  else if (sel == 2) fps_core_lds<8, 16>(tid, lane, wv, M, K, base, pts, s_idx, s_x, s_y, s_z, s_sel, s_key);
  else               fps_core_reg<16, 16>(tid, lane, wv, M, K, base, pts, s_idx, s_k, s_key, s_cxyz);

  __syncthreads();
  const float batf = (float)batch;
  if (sel <= 2) {
    for (int i = tid; i < K; i += nw * 64) {
      int g = (batch * KTOT_ + off + i) * 4;
      u32 p = s_sel[i];
      out2[g + 0] = batf;
      out2[g + 1] = s_x[p];
      out2[g + 2] = s_y[p];
      out2[g + 3] = s_z[p];
    }
  } else {
    for (int i = tid; i < K; i += nw * 64) {
      int g = (batch * KTOT_ + off + i) * 4;
      float4 kk = s_k[i];
      out2[g + 0] = batf;
      out2[g + 1] = kk.x;
      out2[g + 2] = kk.y;
      out2[g + 3] = kk.z;
    }
  }
}

// ---------------------------------------------------------------- BEV + SA + fusion, one block per 4 rows
// SA fast path: range-window candidate scan; first-16-by-index lists rebuilt via
// RANK-BASED SCATTER (broadcast loop over the <=128 hit records): each candidate's
// slot = count of candidates with smaller original index (among flagged for radius 1,
// among all for radius 2). Indices unique -> ranks unique -> slot contents identical
// to the serial min-extract but ~200cy instead of ~3000cy per wave.
__launch_bounds__(256)
__global__ void k_bsf(const float* __restrict__ sf, const float* __restrict__ sfT, int doT,
                      const float* __restrict__ out2, const float* __restrict__ pts,
                      const float* __restrict__ w0, const float* __restrict__ bn0,
                      const float* __restrict__ w1, const float* __restrict__ bn1,
                      const float* __restrict__ fw, const float* __restrict__ fbn,
                      const float* __restrict__ sx, const float* __restrict__ sy,
                      const float* __restrict__ sz, const float* __restrict__ sw,
                      const u32* __restrict__ sid, const u32* __restrict__ bst,
                      float* __restrict__ out1, float* __restrict__ out0) {
#pragma clang fp contract(off)
  __shared__ float s_w0[128];
  __shared__ float s_w1[512];
  __shared__ float s_s0[32], s_m0[32], s_b0[32];
  __shared__ float s_s1[32], s_m1[32], s_b1[32];
  __shared__ float4 s_nb[4][2][16];
  __shared__ float s_row[4][CIN_];
  __shared__ u32 s_li[4][128];                     // hit idx | flag<<31
  __shared__ __align__(16) float4 s_ldt[4][128];   // hit (p-k, feat)

  int tid = threadIdx.x, lane = tid & 63, wv = tid >> 6;

  for (int i = tid; i < 128; i += 256) s_w0[i] = w0[i];
  for (int i = tid; i < 512; i += 256) s_w1[i] = w1[i];
  if (tid < 32) {
    int rad = tid >> 4, c = tid & 15;
    int bb = rad * 64;
    {
      float gg = bn0[bb + c], bbt = bn0[bb + 16 + c];
      float mm = bn0[bb + 32 + c], vv = bn0[bb + 48 + c];
      s_s0[tid] = gg / sqrtf(vv + 1e-5f); s_m0[tid] = mm; s_b0[tid] = bbt;
    }
    {
      float gg = bn1[bb + c], bbt = bn1[bb + 16 + c];
      float mm = bn1[bb + 32 + c], vv = bn1[bb + 48 + c];
      s_s1[tid] = gg / sqrtf(vv + 1e-5f); s_m1[tid] = mm; s_b1[tid] = bbt;
    }
  }
  __syncthreads();

  int g = blockIdx.x * 4 + wv;
  int batch = g >> 11;
  int base = batch * NPTS_;
  float kx = out2[g * 4 + 1];
  float ky = out2[g * 4 + 2];
  float kz = out2[g * 4 + 3];

  // ---------------- BEV
  {
    float x = (kx - 0.0f) / 0.05f / 8.0f;
    float y = (ky - (-40.0f)) / 0.05f / 8.0f;
    int x0 = (int)floorf(x), y0 = (int)floorf(y);
    int x1 = x0 + 1, y1 = y0 + 1;
    x0 = min(max(x0, 0), IMW - 1); x1 = min(max(x1, 0), IMW - 1);
    y0 = min(max(y0, 0), IMH - 1); y1 = min(max(y1, 0), IMH - 1);
    float x0f = (float)x0, x1f = (float)x1, y0f = (float)y0, y1f = (float)y1;
    float wa = (x1f - x) * (y1f - y);
    float wb = (x1f - x) * (y - y0f);
    float wc = (x - x0f) * (y1f - y);
    float wd = (x - x0f) * (y - y0f);
    int oa = y0 * IMW + x0;
    int ob = y1 * IMW + x0;
    int oc = y0 * IMW + x1;
    int od = y1 * IMW + x1;
    if (doT) {
      const float* pb = sfT + (size_t)batch * HW_ * IMC;
      const float4* va = (const float4*)(pb + (size_t)oa * IMC) + lane;
      const float4* vb = (const float4*)(pb + (size_t)ob * IMC) + lane;
      const float4* vc = (const float4*)(pb + (size_t)oc * IMC) + lane;
      const float4* vd = (const float4*)(pb + (size_t)od * IMC) + lane;
      float4 A = *va, B = *vb, C = *vc, D = *vd;
      float4 o;
      o.x = A.x * wa; o.x += B.x * wb; o.x += C.x * wc; o.x += D.x * wd;
      o.y = A.y * wa; o.y += B.y * wb; o.y += C.y * wc; o.y += D.y * wd;
      o.z = A.z * wa; o.z += B.z * wb; o.z += C.z * wc; o.z += D.z * wd;
      o.w = A.w * wa; o.w += B.w * wb; o.w += C.w * wc; o.w += D.w * wd;
      *(float4*)&out1[(size_t)g * CIN_ + lane * 4] = o;
      *(float4*)&s_row[wv][lane * 4] = o;
    } else {
      const float* pb = sf + (size_t)batch * IMC * HW_;
      for (int j = 0; j < 4; ++j) {
        int c = lane * 4 + j;
        const float* pc = pb + (size_t)c * HW_;
        float o = pc[oa] * wa;
        o += pc[ob] * wb;
        o += pc[oc] * wc;
        o += pc[od] * wd;
        out1[(size_t)g * CIN_ + c] = o;
        s_row[wv][c] = o;
      }
    }
  }

  // ---------------- SA
  int c1 = 0, c2 = 0;
  bool fast = false;
  if (doT) {
    const float INV = (float)NBKT / RMAX;
    float rk = sqrtf(kx * kx + ky * ky);
    int blo = max(0, (int)((rk - 2.001f) * INV));
    int bhi = min(NBKT - 1, (int)((rk + 2.001f) * INV));
    const u32* bb = bst + batch * (NBKT + 1);
    int S0 = (int)bb[blo], S1 = (int)bb[bhi + 1];
    const float* SX = sx + (size_t)batch * NPTS_;
    const float* SY = sy + (size_t)batch * NPTS_;
    const float* SZ = sz + (size_t)batch * NPTS_;
    const float* SW = sw + (size_t)batch * NPTS_;
    const u32* SI = sid + (size_t)batch * NPTS_;
    for (int s0 = S0; s0 < S1; s0 += 64) {
      int sl = s0 + lane;
      bool vld = sl < S1;
      int slc = vld ? sl : S0;
      float px = SX[slc], py = SY[slc], pz = SZ[slc], pw = SW[slc];
      u32 pid = SI[slc];
      float dx = kx - px;
      float dy = ky - py;
      float dz = kz - pz;
      float d = dx * dx;
      d += dy * dy;
      d += dz * dz;
      bool h1 = vld && (d < 1.0f);
      bool h2 = vld && (d < 4.0f);
      u64 m2 = __ballot(h2);
      int below = __builtin_amdgcn_mbcnt_hi((u32)(m2 >> 32),
                    __builtin_amdgcn_mbcnt_lo((u32)m2, 0));
      int rank = c2 + below;
      if (h2 && rank < 128) {
        s_li[wv][rank] = pid | (h1 ? 0x80000000u : 0u);
        s_ldt[wv][rank] = make_float4(-dx, -dy, -dz, pw);   // -dx == px-kx bit-exact
      }
      c2 += __popcll(m2);
      c1 += __popcll(__ballot(h1));
    }
    fast = (c2 <= 128);
    if (fast) {
      // ---- rank-based scatter (identical output to serial min-extract)
      int n = c2;
      const u32 BIG = 0x7FFFFFFFu;
      u32 e0 = (lane < n) ? s_li[wv][lane] : 0xFFFFFFFFu;
      u32 e1 = (lane + 64 < n) ? s_li[wv][lane + 64] : 0xFFFFFFFFu;
      bool v0 = (e0 != 0xFFFFFFFFu), v1 = (e1 != 0xFFFFFFFFu);
      bool f0 = v0 && (e0 & 0x80000000u), f1 = v1 && (e1 & 0x80000000u);
      u32 i0 = e0 & BIG, i1 = e1 & BIG;
      int r0a = 0, r0b = 0, r1a = 0, r1b = 0;
      for (int j = 0; j < n; ++j) {
        u32 vj = s_li[wv][j];          // broadcast LDS read (all lanes same addr)
        u32 ij = vj & BIG;
        bool fj = (vj & 0x80000000u) != 0u;
        bool l0 = ij < i0;
        bool l1 = ij < i1;
        r0b += l0 ? 1 : 0;
        r1b += l1 ? 1 : 0;
        r0a += (fj && l0) ? 1 : 0;
        r1a += (fj && l1) ? 1 : 0;
      }
      if (f0 && r0a < 16) s_nb[wv][0][r0a] = s_ldt[wv][lane];
      if (f1 && r1a < 16) s_nb[wv][0][r1a] = s_ldt[wv][lane + 64];
      if (v0 && r0b < 16) s_nb[wv][1][r0b] = s_ldt[wv][lane];
      if (v1 && r1b < 16) s_nb[wv][1][r1b] = s_ldt[wv][lane + 64];
    }
  }
  if (!fast) {
    // full index-order scan (fallback / !doT) — verified R5 logic
    c1 = 0; c2 = 0;
    for (int r = 0; r < NPTS_ / 64; ++r) {
      int gi = (base + r * 64 + lane) * 5;
      float px = pts[gi + 1];
      float py = pts[gi + 2];
      float pz = pts[gi + 3];
      float pw = pts[gi + 4];
      float dx = kx - px;
      float dy = ky - py;
      float dz = kz - pz;
      float d = dx * dx;
      d += dy * dy;
      d += dz * dz;
      bool h1 = d < 1.0f;
      bool h2 = d < 4.0f;
      u64 m1 = __ballot(h1);
      u64 m2 = __ballot(h2);
      int below1 = __builtin_amdgcn_mbcnt_hi((u32)(m1 >> 32),
                    __builtin_amdgcn_mbcnt_lo((u32)m1, 0));
      int below2 = __builtin_amdgcn_mbcnt_hi((u32)(m2 >> 32),
                    __builtin_amdgcn_mbcnt_lo((u32)m2, 0));
      int rank1 = c1 + below1;
      int rank2 = c2 + below2;
      if (h1 && rank1 < 16) s_nb[wv][0][rank1] = make_float4(px - kx, py - ky, pz - kz, pw);
      if (h2 && rank2 < 16) s_nb[wv][1][rank2] = make_float4(px - kx, py - ky, pz - kz, pw);
      c1 += __popcll(m1);
      c2 += __popcll(m2);
      if (c1 >= 16 && c2 >= 16) break;
    }
  }

  int myrad = (lane >> 4) & 1, myslot = lane & 15;
  int cnt = (myrad == 0) ? min(c1, 16) : min(c2, 16);
  float gx = 0.f, gy = 0.f, gz = 0.f, gf = 0.f;
  if (lane < 32 && cnt > 0) {
    int src = (myslot < cnt) ? myslot : 0;
    float4 nb = s_nb[wv][myrad][src];
    gx = nb.x; gy = nb.y; gz = nb.z; gf = nb.w;
  }
  const float* W0 = s_w0 + myrad * 64;
  const float* W1 = s_w1 + myrad * 256;
  int bc = myrad * 16;
  float h1v[16];
  for (int c = 0; c < 16; ++c) {
    float a = gx * W0[c];
    a += gy * W0[16 + c];
    a += gz * W0[32 + c];
    a += gf * W0[48 + c];
    h1v[c] = fmaxf((a - s_m0[bc + c]) * s_s0[bc + c] + s_b0[bc + c], 0.f);
  }
  for (int c = 0; c < 16; ++c) {
    float a = 0.f;
    for (int k = 0; k < 16; ++k) a += h1v[k] * W1[k * 16 + c];
    float h2v = fmaxf((a - s_m1[bc + c]) * s_s1[bc + c] + s_b1[bc + c], 0.f);
    h2v = fmaxf(h2v, __shfl_xor(h2v, 1));
    h2v = fmaxf(h2v, __shfl_xor(h2v, 2));
    h2v = fmaxf(h2v, __shfl_xor(h2v, 4));
    h2v = fmaxf(h2v, __shfl_xor(h2v, 8));
    if (lane < 32 && myslot == 0) {
      int col = 256 + myrad * 16 + c;
      out1[(size_t)g * CIN_ + col] = h2v;
      s_row[wv][col] = h2v;
    }
  }

  // ---------------- fusion
  __syncthreads();
  {
    int col = tid & 127, rh = tid >> 7;
    float a0 = 0.f, a1 = 0.f;
    for (int k = 0; k < CIN_; ++k) {
      float w = fw[k * COUT_ + col];
      a0 += s_row[rh][k] * w;
      a1 += s_row[rh + 2][k] * w;
    }
    float gg = fbn[col], bb = fbn[COUT_ + col];
    float mm = fbn[2 * COUT_ + col], vv = fbn[3 * COUT_ + col];
    float sc = gg / sqrtf(vv + 1e-5f);
    int g0 = blockIdx.x * 4;
    out0[(size_t)(g0 + rh) * COUT_ + col] = fmaxf((a0 - mm) * sc + bb, 0.f);
    out0[(size_t)(g0 + rh + 2) * COUT_ + col] = fmaxf((a1 - mm) * sc + bb, 0.f);
  }
}

// ---------------------------------------------------------------- launch
extern "C" void kernel_launch(void* const* d_in, const int* in_sizes, int n_in,
                              void* d_out, int out_size, void* d_ws, size_t ws_size,
                              hipStream_t stream) {
  const float* points = (const float*)d_in[0];
  const float* rng    = (const float*)d_in[1];
  const float* sf     = (const float*)d_in[2];
  const float* w0     = (const float*)d_in[3];
  const float* bn0    = (const float*)d_in[4];
  const float* w1     = (const float*)d_in[5];
  const float* bn1    = (const float*)d_in[6];
  const float* fw     = (const float*)d_in[7];
  const float* fbn    = (const float*)d_in[8];

  float* out0 = (float*)d_out;                         // fused [4096,128]
  float* out1 = out0 + (size_t)ROWS_ * COUT_;          // feats [4096,288]
  float* out2 = out1 + (size_t)ROWS_ * CIN_;           // point_coords [4096,4]

  const size_t SFT_CNT = (size_t)NB * IMC * HW_;       // floats
  const size_t SORT_CNT = (size_t)NB * NPTS_;          // per array
  const size_t need = (SFT_CNT + 5 * SORT_CNT + NB * (NBKT + 1)) * 4;
  const int doT = (d_ws != nullptr && ws_size >= need) ? 1 : 0;
  float* sfT = (float*)d_ws;
  float* sx = sfT + SFT_CNT;
  float* sy = sx + SORT_CNT;
  float* sz = sy + SORT_CNT;
  float* sw = sz + SORT_CNT;
  u32* sid = (u32*)(sw + SORT_CNT);
  u32* bst = sid + SORT_CNT;

  // blocks 0..5 FPS; 6..4405 transpose; 4406..4407 range sort (all hidden under FPS)
  k_fps<<<doT ? (6 + NB * 2200 + NB) : 6, 1024, 0, stream>>>(
      points, rng, out2, sf, sfT, sx, sy, sz, sw, sid, bst);
  k_bsf<<<ROWS_ / 4, 256, 0, stream>>>(sf, sfT, doT, out2, points, w0, bn0, w1, bn1,
                                       fw, fbn, sx, sy, sz, sw, sid, bst, out1, out0);
}